// Round 11
// baseline (393.991 us; speedup 1.0000x reference)
//
#include <hip/hip_runtime.h>

#define BB 32
#define IDF 64
#define QL 16384
#define CDF 768
#define SL 18
#define SLP 20             // padded row stride for sT rows
#define CLP 21             // odd stride for ctx_l -> conflict-free b32 reads
#define ADIM 100

// ---------------- Kernel A: sT[b,i,s] = sum_c wic[i,c] * ctx[b,c,s]; out init.
__global__ __launch_bounds__(256, 2) void kA_source(
        const float* __restrict__ ctx,      // [B, CDF, SL]
        const float* __restrict__ wic,      // [IDF, CDF]
        const float* __restrict__ fc_b,     // [ADIM]
        float* __restrict__ sT,             // ws: [B, IDF, SLP]
        float* __restrict__ out)            // [B, ADIM]
{
    __shared__ float ctx_l[CDF * CLP];     // 64512 B
    const int blk  = blockIdx.x;
    const int tid  = threadIdx.x;
    const int wave = tid >> 6;
    const int lane = tid & 63;
    const int b = blk >> 4;
    const int g = blk & 15;

    if (blk < 13) {
        const int t = blk * 256 + tid;
        if (t < BB * ADIM) out[t] = fc_b[t % ADIM];
    }

    const float* ctxb = ctx + (size_t)b * CDF * SL;
    for (int t = tid; t < CDF * SL; t += 256) {
        const int c = t / SL;
        const int s = t - c * SL;
        ctx_l[c * CLP + s] = ctxb[t];
    }
    __syncthreads();

    const int i = g * 4 + wave;
    const float* wrow = wic + (size_t)i * CDF;

    float acc[SL];
#pragma unroll
    for (int s = 0; s < SL; s++) acc[s] = 0.f;

#pragma unroll 2
    for (int k = 0; k < CDF / 64; k++) {
        const int c = k * 64 + lane;
        const float wv = wrow[c];
#pragma unroll
        for (int s = 0; s < SL; s++) acc[s] += wv * ctx_l[c * CLP + s];
    }
#pragma unroll
    for (int s = 0; s < SL; s++) {
        float a = acc[s];
#pragma unroll
        for (int off = 32; off; off >>= 1) a += __shfl_xor(a, off, 64);
        if (lane == 0) sT[((size_t)b * IDF + i) * SLP + s] = a;
    }
}

// ---------------- Kernel B: scores -> softmax -> dot(v) -> wq (LDS) -> fc dot -> out.
// grid = (32 qt, 32 b), block 512 (8 waves), 1 q/thread. __launch_bounds__(512,8)
// caps VGPR at 64 -> 8 waves/SIMD, 32 waves/CU: TLP does the latency hiding
// (kB_ld ablation: this load stream runs 5.5 TB/s at high occupancy with a small
// register footprint). Per-thread state: sc[18] scalars + 8-float prefetch —
// no AGPR round-trips, no asm pipeline. st from LDS broadcast reads.
__global__ __launch_bounds__(512, 8) void kB_attn(
        const float* __restrict__ inp,     // [B, IDF, QL]
        const float* __restrict__ sT,      // ws: [B, IDF, SLP]
        const float* __restrict__ conv_w,  // [IDF]
        const float* __restrict__ conv_b,  // [1]
        const float* __restrict__ fcw,     // [ADIM, QL]
        float* __restrict__ out)           // [B, ADIM]
{
    __shared__ __align__(16) float st_l[IDF * SLP];   // 5120 B
    __shared__ float v_l[SL];
    __shared__ __align__(16) float wq_l[512];
    const int b   = blockIdx.y;
    const int qt  = blockIdx.x;
    const int tid = threadIdx.x;
    const int wave = tid >> 6;
    const int lane = tid & 63;

    {   // stage st block into LDS (coalesced)
        const float* stg = sT + (size_t)b * IDF * SLP;
#pragma unroll
        for (int t = tid; t < IDF * SLP; t += 512) st_l[t] = stg[t];
    }
    __syncthreads();

    if (tid < SL) {                        // v[s] = sum_i cw[i]*st[i][s]
        float a = 0.f;
        for (int i = 0; i < IDF; i++) a += conv_w[i] * st_l[i * SLP + tid];
        v_l[tid] = a;
    }

    // this thread's query column: one float per row, stride QL
    const float* gq = inp + (size_t)b * IDF * QL + (size_t)qt * 512 + tid;

    float sc[SL];
#pragma unroll
    for (int s = 0; s < SL; s++) sc[s] = 0.f;

    float xcur[8], xnxt[8];
#pragma unroll
    for (int r = 0; r < 8; r++) xcur[r] = gq[(size_t)r * QL];

#pragma unroll
    for (int k = 0; k < 8; k++) {
        if (k < 7) {
#pragma unroll
            for (int r = 0; r < 8; r++) xnxt[r] = gq[(size_t)(k * 8 + 8 + r) * QL];
        }
#pragma unroll
        for (int r = 0; r < 8; r++) {
            const float* row_ = &st_l[(k * 8 + r) * SLP];
            const float4 t0 = *(const float4*)(row_ + 0);
            const float4 t1 = *(const float4*)(row_ + 4);
            const float4 t2 = *(const float4*)(row_ + 8);
            const float4 t3 = *(const float4*)(row_ + 12);
            const float2 t4 = *(const float2*)(row_ + 16);
            const float xv = xcur[r];
            sc[0]  += xv * t0.x;  sc[1]  += xv * t0.y;
            sc[2]  += xv * t0.z;  sc[3]  += xv * t0.w;
            sc[4]  += xv * t1.x;  sc[5]  += xv * t1.y;
            sc[6]  += xv * t1.z;  sc[7]  += xv * t1.w;
            sc[8]  += xv * t2.x;  sc[9]  += xv * t2.y;
            sc[10] += xv * t2.z;  sc[11] += xv * t2.w;
            sc[12] += xv * t3.x;  sc[13] += xv * t3.y;
            sc[14] += xv * t3.z;  sc[15] += xv * t3.w;
            sc[16] += xv * t4.x;  sc[17] += xv * t4.y;
        }
#pragma unroll
        for (int r = 0; r < 8; r++) xcur[r] = xnxt[r];
    }

    __syncthreads();       // v_l visibility; wq_l reuse guard

    float m = sc[0];
#pragma unroll
    for (int s = 1; s < SL; s++) m = fmaxf(m, sc[s]);
    float l = 0.f, o = 0.f;
#pragma unroll
    for (int s = 0; s < SL; s++) {
        const float p = __expf(sc[s] - m);
        l += p;
        o += p * v_l[s];
    }
    wq_l[tid] = o / l + conv_b[0];
    __syncthreads();

    // ---- fused kC: out[b,a] += dot(fcw[a, qt*512 : +512], wq_l)
    // 8 waves; wave w handles a = 8j + w (13 rows for w<4, else 12).
    const float4 w0 = *(const float4*)(&wq_l[lane * 4]);
    const float4 w1 = *(const float4*)(&wq_l[256 + lane * 4]);
    const float* fbase = fcw + (size_t)qt * 512 + lane * 4;
#pragma unroll 2
    for (int j = 0; j < 13; j++) {
        const int a = j * 8 + wave;
        if (a < ADIM) {
            const float4 f0 = *(const float4*)(fbase + (size_t)a * QL);
            const float4 f1 = *(const float4*)(fbase + (size_t)a * QL + 256);
            float r = f0.x * w0.x + f0.y * w0.y + f0.z * w0.z + f0.w * w0.w
                    + f1.x * w1.x + f1.y * w1.y + f1.z * w1.z + f1.w * w1.w;
#pragma unroll
            for (int off = 32; off; off >>= 1) r += __shfl_xor(r, off, 64);
            if (lane == 0) atomicAdd(&out[b * ADIM + a], r);
        }
    }
}

extern "C" void kernel_launch(void* const* d_in, const int* in_sizes, int n_in,
                              void* d_out, int out_size, void* d_ws, size_t ws_size,
                              hipStream_t stream)
{
    const float* inputs     = (const float*)d_in[0];  // [32,64,128,128]
    const float* context    = (const float*)d_in[1];  // [32,768,18]
    const float* conv_ctx_w = (const float*)d_in[2];  // [64,768]
    const float* conv_w     = (const float*)d_in[3];  // [64]
    const float* conv_b     = (const float*)d_in[4];  // [1]
    const float* fc_w       = (const float*)d_in[5];  // [100,16384]
    const float* fc_b       = (const float*)d_in[6];  // [100]
    float* out = (float*)d_out;

    float* ws = (float*)d_ws;
    float* sT = ws;                                   // 40960 floats

    kA_source<<<dim3(512), dim3(256), 0, stream>>>(context, conv_ctx_w, fc_b, sT, out);
    kB_attn<<<dim3(32, BB), dim3(512), 0, stream>>>(inputs, sT, conv_w, conv_b, fc_w, out);
}

// Round 12
// 235.134 us; speedup vs baseline: 1.6756x; 1.6756x over previous
//
#include <hip/hip_runtime.h>

#define BB 32
#define IDF 64
#define QL 16384
#define CDF 768
#define SL 18
#define SLP 20             // padded row stride for sT rows
#define CLP 21             // odd stride for ctx_l -> conflict-free b32 reads
#define ADIM 100

// ---------------- Kernel A: sT[b,i,s] = sum_c wic[i,c] * ctx[b,c,s]; out init.
__global__ __launch_bounds__(256, 2) void kA_source(
        const float* __restrict__ ctx,      // [B, CDF, SL]
        const float* __restrict__ wic,      // [IDF, CDF]
        const float* __restrict__ fc_b,     // [ADIM]
        float* __restrict__ sT,             // ws: [B, IDF, SLP]
        float* __restrict__ out)            // [B, ADIM]
{
    __shared__ float ctx_l[CDF * CLP];     // 64512 B
    const int blk  = blockIdx.x;
    const int tid  = threadIdx.x;
    const int wave = tid >> 6;
    const int lane = tid & 63;
    const int b = blk >> 4;
    const int g = blk & 15;

    if (blk < 13) {
        const int t = blk * 256 + tid;
        if (t < BB * ADIM) out[t] = fc_b[t % ADIM];
    }

    const float* ctxb = ctx + (size_t)b * CDF * SL;
    for (int t = tid; t < CDF * SL; t += 256) {
        const int c = t / SL;
        const int s = t - c * SL;
        ctx_l[c * CLP + s] = ctxb[t];
    }
    __syncthreads();

    const int i = g * 4 + wave;
    const float* wrow = wic + (size_t)i * CDF;

    float acc[SL];
#pragma unroll
    for (int s = 0; s < SL; s++) acc[s] = 0.f;

#pragma unroll 2
    for (int k = 0; k < CDF / 64; k++) {
        const int c = k * 64 + lane;
        const float wv = wrow[c];
#pragma unroll
        for (int s = 0; s < SL; s++) acc[s] += wv * ctx_l[c * CLP + s];
    }
#pragma unroll
    for (int s = 0; s < SL; s++) {
        float a = acc[s];
#pragma unroll
        for (int off = 32; off; off >>= 1) a += __shfl_xor(a, off, 64);
        if (lane == 0) sT[((size_t)b * IDF + i) * SLP + s] = a;
    }
}

// ---------------- Kernel B: scores -> softmax -> dot(v) -> wq (LDS) -> fc dot -> out.
// grid = (32 qt, 32 b), block 512 (8 waves), 1 q/thread.
// __launch_bounds__(512, 4): 128-VGPR budget — round-11's (512,8) made the
// allocator squeeze to 32 VGPR and spill all 34 live floats (423 MB scratch
// writes, 235 us). ~50 VGPR actual usage -> 6-8 waves/SIMD from usage, no spill.
// TLP does the latency hiding (kB_ld ablation: this load stream = 5.5 TB/s).
__global__ __launch_bounds__(512, 4) void kB_attn(
        const float* __restrict__ inp,     // [B, IDF, QL]
        const float* __restrict__ sT,      // ws: [B, IDF, SLP]
        const float* __restrict__ conv_w,  // [IDF]
        const float* __restrict__ conv_b,  // [1]
        const float* __restrict__ fcw,     // [ADIM, QL]
        float* __restrict__ out)           // [B, ADIM]
{
    __shared__ __align__(16) float st_l[IDF * SLP];   // 5120 B
    __shared__ float v_l[SL];
    __shared__ __align__(16) float wq_l[512];
    const int b   = blockIdx.y;
    const int qt  = blockIdx.x;
    const int tid = threadIdx.x;
    const int wave = tid >> 6;
    const int lane = tid & 63;

    {   // stage st block into LDS (coalesced)
        const float* stg = sT + (size_t)b * IDF * SLP;
#pragma unroll
        for (int t = tid; t < IDF * SLP; t += 512) st_l[t] = stg[t];
    }
    __syncthreads();

    if (tid < SL) {                        // v[s] = sum_i cw[i]*st[i][s]
        float a = 0.f;
        for (int i = 0; i < IDF; i++) a += conv_w[i] * st_l[i * SLP + tid];
        v_l[tid] = a;
    }

    // this thread's query column: one float per row, stride QL
    const float* gq = inp + (size_t)b * IDF * QL + (size_t)qt * 512 + tid;

    float sc[SL];
#pragma unroll
    for (int s = 0; s < SL; s++) sc[s] = 0.f;

    float xcur[8], xnxt[8];
#pragma unroll
    for (int r = 0; r < 8; r++) xcur[r] = gq[(size_t)r * QL];

#pragma unroll
    for (int k = 0; k < 8; k++) {
        if (k < 7) {
#pragma unroll
            for (int r = 0; r < 8; r++) xnxt[r] = gq[(size_t)(k * 8 + 8 + r) * QL];
        }
#pragma unroll
        for (int r = 0; r < 8; r++) {
            const float* row_ = &st_l[(k * 8 + r) * SLP];
            const float4 t0 = *(const float4*)(row_ + 0);
            const float4 t1 = *(const float4*)(row_ + 4);
            const float4 t2 = *(const float4*)(row_ + 8);
            const float4 t3 = *(const float4*)(row_ + 12);
            const float2 t4 = *(const float2*)(row_ + 16);
            const float xv = xcur[r];
            sc[0]  += xv * t0.x;  sc[1]  += xv * t0.y;
            sc[2]  += xv * t0.z;  sc[3]  += xv * t0.w;
            sc[4]  += xv * t1.x;  sc[5]  += xv * t1.y;
            sc[6]  += xv * t1.z;  sc[7]  += xv * t1.w;
            sc[8]  += xv * t2.x;  sc[9]  += xv * t2.y;
            sc[10] += xv * t2.z;  sc[11] += xv * t2.w;
            sc[12] += xv * t3.x;  sc[13] += xv * t3.y;
            sc[14] += xv * t3.z;  sc[15] += xv * t3.w;
            sc[16] += xv * t4.x;  sc[17] += xv * t4.y;
        }
#pragma unroll
        for (int r = 0; r < 8; r++) xcur[r] = xnxt[r];
    }

    __syncthreads();       // v_l visibility; wq_l reuse guard

    float m = sc[0];
#pragma unroll
    for (int s = 1; s < SL; s++) m = fmaxf(m, sc[s]);
    float l = 0.f, o = 0.f;
#pragma unroll
    for (int s = 0; s < SL; s++) {
        const float p = __expf(sc[s] - m);
        l += p;
        o += p * v_l[s];
    }
    wq_l[tid] = o / l + conv_b[0];
    __syncthreads();

    // ---- fused kC: out[b,a] += dot(fcw[a, qt*512 : +512], wq_l)
    // 8 waves; wave w handles a = 8j + w (13 rows for w<4, else 12).
    const float4 w0 = *(const float4*)(&wq_l[lane * 4]);
    const float4 w1 = *(const float4*)(&wq_l[256 + lane * 4]);
    const float* fbase = fcw + (size_t)qt * 512 + lane * 4;
#pragma unroll 2
    for (int j = 0; j < 13; j++) {
        const int a = j * 8 + wave;
        if (a < ADIM) {
            const float4 f0 = *(const float4*)(fbase + (size_t)a * QL);
            const float4 f1 = *(const float4*)(fbase + (size_t)a * QL + 256);
            float r = f0.x * w0.x + f0.y * w0.y + f0.z * w0.z + f0.w * w0.w
                    + f1.x * w1.x + f1.y * w1.y + f1.z * w1.z + f1.w * w1.w;
#pragma unroll
            for (int off = 32; off; off >>= 1) r += __shfl_xor(r, off, 64);
            if (lane == 0) atomicAdd(&out[b * ADIM + a], r);
        }
    }
}

extern "C" void kernel_launch(void* const* d_in, const int* in_sizes, int n_in,
                              void* d_out, int out_size, void* d_ws, size_t ws_size,
                              hipStream_t stream)
{
    const float* inputs     = (const float*)d_in[0];  // [32,64,128,128]
    const float* context    = (const float*)d_in[1];  // [32,768,18]
    const float* conv_ctx_w = (const float*)d_in[2];  // [64,768]
    const float* conv_w     = (const float*)d_in[3];  // [64]
    const float* conv_b     = (const float*)d_in[4];  // [1]
    const float* fc_w       = (const float*)d_in[5];  // [100,16384]
    const float* fc_b       = (const float*)d_in[6];  // [100]
    float* out = (float*)d_out;

    float* ws = (float*)d_ws;
    float* sT = ws;                                   // 40960 floats

    kA_source<<<dim3(512), dim3(256), 0, stream>>>(context, conv_ctx_w, fc_b, sT, out);
    kB_attn<<<dim3(32, BB), dim3(512), 0, stream>>>(inputs, sT, conv_w, conv_b, fc_w, out);
}